// Round 15
// baseline (150.591 us; speedup 1.0000x reference)
//
#include <hip/hip_runtime.h>
#include <math.h>

#define BTOT   32768
#define LAT    128
#define H      17
#define G4     68      // 4*H
#define TSTEPS 50
#define NPR    102     // projection rows: 68 (W_ih) + 17 (W_h0) + 17 (W_c0)
#define WPAD   40      // Wbuf row stride (k-quarter staging)
#define XPAD   132
#define WTS    72      // Wt row stride in floats (17*4 + 4 pad)

#define NW     8              // waves per block
#define RPB    48             // 6 rows per wave: set A rows rl, set B rows rl+3
#define TPB    512

#define LOG2E 1.4426950408889634f

// x_tile stride 132: rows r,r+8 alias -> 2-bit XOR key (proven R14: 2.98M).
#define XSWZ(r, c4)   ((c4) ^ ((((r) >> 3) & 3) << 2))
// Wbuf stride 40: rows r,r+4 alias -> key on bits 2-3 (proven R14).
#define WSWZ(row, c4) ((c4) ^ ((((row) >> 2) & 3) << 2))

// v_exp_f32 IS exp2 -- W/xg pre-scaled by -log2e (i,f,o) / +2log2e (g).
__device__ __forceinline__ float exp2g(float x) {
    float r; asm("v_exp_f32 %0, %1" : "=v"(r) : "v"(x)); return r;
}

// One k of the dot: ds_read_b128 -> (Wi,Wf,Wg,Wo)[j][k], 4 fmaf with h_k.
// W never lives in registers beyond this use (R15 core idea: the AGPR-copy
// tax that pinned R6..R14 at ~131-154us is removed by streaming W from LDS).
#define KQ(KK, HV) do { \
    float4 w_ = *(const float4*)(wp + (KK) * WTS); \
    ai = fmaf(w_.x, (HV), ai); af = fmaf(w_.y, (HV), af); \
    ag = fmaf(w_.z, (HV), ag); ao = fmaf(w_.w, (HV), ao); } while (0)

#define SETSTEP(S, HB, OR, VS) do { \
    float4 F0 = *(const float4*)&(HB)[0]; \
    float4 F1 = *(const float4*)&(HB)[4]; \
    float4 F2 = *(const float4*)&(HB)[8]; \
    float4 F3 = *(const float4*)&(HB)[12]; \
    float  F4 = (HB)[16]; \
    float ai = xgi[S], af = xgf[S], ag = xgg[S], ao = xgo[S]; \
    KQ(0,  F0.x); KQ(1,  F0.y); KQ(2,  F0.z); KQ(3,  F0.w); \
    KQ(4,  F1.x); KQ(5,  F1.y); KQ(6,  F1.z); KQ(7,  F1.w); \
    KQ(8,  F2.x); KQ(9,  F2.y); KQ(10, F2.z); KQ(11, F2.w); \
    KQ(12, F3.x); KQ(13, F3.y); KQ(14, F3.z); KQ(15, F3.w); \
    KQ(16, F4); \
    const float ig = __builtin_amdgcn_rcpf(1.0f + exp2g(ai)); \
    const float fg = __builtin_amdgcn_rcpf(1.0f + exp2g(af)); \
    const float og = __builtin_amdgcn_rcpf(1.0f + exp2g(ao)); \
    const float tg = __builtin_amdgcn_rcpf(exp2g(ag) + 1.0f); \
    cS[S] = fmaf(fg, cS[S], ig * fmaf(-2.0f, tg, 1.0f)); \
    const float tc = __builtin_amdgcn_rcpf(exp2g(cS[S] * (2.0f * LOG2E)) + 1.0f); \
    hS[S] = og * fmaf(-2.0f, tc, 1.0f); \
    if (active) (HB)[j] = hS[S]; \
    if (VS) (OR)[0] = hS[S]; \
    (OR) += H; } while (0)

__global__ __launch_bounds__(TPB, 2)
void lstm_fused(const float* __restrict__ x,
                const float* __restrict__ W_h0, const float* __restrict__ b_h0,
                const float* __restrict__ W_c0, const float* __restrict__ b_c0,
                const float* __restrict__ W_ih, const float* __restrict__ W_hh,
                const float* __restrict__ b_ih, const float* __restrict__ b_hh,
                float* __restrict__ out)
{
    __shared__ __align__(16) float x_tile[RPB][XPAD];   // 25.3 KB
    __shared__ __align__(16) float Wbuf[NPR][WPAD];     // 16.3 KB (one k-quarter)
    __shared__ __align__(16) float Wt[H * WTS];         //  4.9 KB (W_hh transposed, gate-interleaved, pre-scaled)
    __shared__ __align__(16) float hbuf[NW][6][20];     //  3.8 KB
    // total 50.4 KB -> 3 blocks/CU; grid 683 at 2.67 blocks/CU -> co-resident

    const int t    = threadIdx.x;
    const int w    = t >> 6;
    const int lane = t & 63;
    const bool active = lane < 3 * H;         // 51
    const int rl = active ? (lane / H) : 0;   // 0..2
    const int j  = active ? (lane % H) : 0;   // 0..16
    const int r0 = w * 6 + rl;                // set-A local row; set B = r0+3
    const int grow0 = blockIdx.x * RPB;

    int gA = grow0 + r0,     gB = grow0 + r0 + 3;
    const bool vA = active && (gA < BTOT), vB = active && (gB < BTOT);
    if (gA >= BTOT) gA = BTOT - 1;
    if (gB >= BTOT) gB = BTOT - 1;

    // ---- stage x tile + Wt (transposed, pre-scaled W_hh) ----
    for (int i = t; i < RPB * 32; i += TPB) {
        int rr = i >> 5, c4 = (i & 31) * 4;
        int gr = grow0 + rr; if (gr >= BTOT) gr = BTOT - 1;
        *(float4*)&x_tile[rr][XSWZ(rr, c4)] = *(const float4*)(x + (size_t)gr * LAT + c4);
    }
    for (int i = t; i < G4 * H; i += TPB) {   // 1156 elements
        int row = i / H;            // g*17 + jj
        int k   = i - row * H;      // 0..16
        int g   = row / H;          // 0..3
        int jj  = row - g * H;      // 0..16
        const float sc = (g == 2) ? (2.0f * LOG2E) : (-LOG2E);
        Wt[k * WTS + jj * 4 + g] = W_hh[i] * sc;
    }

    // ---- phase 1: projections for both sets, four k-quarters of 32 ----
    float acc[12];
#pragma unroll
    for (int s = 0; s < 12; ++s) acc[s] = 0.0f;
    const int rows6[6] = { j, 17 + j, 34 + j, 51 + j, 68 + j, 85 + j };
    for (int qh = 0; qh < 4; ++qh) {
        __syncthreads();  // qh=0: x_tile/Wt ready; else WAR on Wbuf
        for (int i = t; i < NPR * 8; i += TPB) {
            int row = i >> 3, c4 = (i & 7) * 4;
            const float* src = (row < G4) ? (W_ih + row * LAT)
                             : (row < 85) ? (W_h0 + (row - G4) * LAT)
                                          : (W_c0 + (row - 85) * LAT);
            *(float4*)&Wbuf[row][WSWZ(row, c4)] = *(const float4*)(src + qh * 32 + c4);
        }
        __syncthreads();
        for (int kb = 0; kb < 8; ++kb) {
            const int xc = qh * 32 + kb * 4;
            float4 xa = *(const float4*)&x_tile[r0][XSWZ(r0, xc)];
            float4 xb = *(const float4*)&x_tile[r0 + 3][XSWZ(r0 + 3, xc)];
#pragma unroll
            for (int p = 0; p < 6; ++p) {
                const int row = rows6[p];
                float4 wv = *(const float4*)&Wbuf[row][WSWZ(row, kb * 4)];
                acc[p]     = fmaf(xa.x, wv.x, acc[p]);
                acc[p]     = fmaf(xa.y, wv.y, acc[p]);
                acc[p]     = fmaf(xa.z, wv.z, acc[p]);
                acc[p]     = fmaf(xa.w, wv.w, acc[p]);
                acc[6 + p] = fmaf(xb.x, wv.x, acc[6 + p]);
                acc[6 + p] = fmaf(xb.y, wv.y, acc[6 + p]);
                acc[6 + p] = fmaf(xb.z, wv.z, acc[6 + p]);
                acc[6 + p] = fmaf(xb.w, wv.w, acc[6 + p]);
            }
        }
    }

    // ---- biases + exp2 pre-scaling ----
    const float bi0 = b_ih[j]      + b_hh[j];
    const float bi1 = b_ih[17 + j] + b_hh[17 + j];
    const float bi2 = b_ih[34 + j] + b_hh[34 + j];
    const float bi3 = b_ih[51 + j] + b_hh[51 + j];
    float xgi[2], xgf[2], xgg[2], xgo[2], hS[2], cS[2];
#pragma unroll
    for (int s = 0; s < 2; ++s) {
        xgi[s] = (acc[s * 6 + 0] + bi0) * (-LOG2E);
        xgf[s] = (acc[s * 6 + 1] + bi1) * (-LOG2E);
        xgg[s] = (acc[s * 6 + 2] + bi2) * (2.0f * LOG2E);
        xgo[s] = (acc[s * 6 + 3] + bi3) * (-LOG2E);
        hS[s]  =  acc[s * 6 + 4] + b_h0[j];
        cS[s]  =  acc[s * 6 + 5] + b_c0[j];
    }

    // ---- phase 2: zero barriers; W streamed from LDS per use ----
    float* hbA = &hbuf[w][rl][0];
    float* hbB = &hbuf[w][3 + rl][0];
    float* orowA = out + (size_t)gA * (TSTEPS * H) + j;
    float* orowB = out + (size_t)gB * (TSTEPS * H) + j;
    const float* wtp = &Wt[j * 4];

    if (active) { hbA[j] = hS[0]; hbB[j] = hS[1]; }

    for (int tt = 0; tt < TSTEPS; ++tt) {
        int zoff = 0;
        asm volatile("" : "+s"(zoff));       // opaque 0: W reads not hoistable/LICM-able
        const float* wp = wtp + zoff;
        SETSTEP(0, hbA, orowA, vA);
        SETSTEP(1, hbB, orowB, vB);
    }
}

extern "C" void kernel_launch(void* const* d_in, const int* in_sizes, int n_in,
                              void* d_out, int out_size, void* d_ws, size_t ws_size,
                              hipStream_t stream)
{
    const float* x    = (const float*)d_in[0];
    const float* W_h0 = (const float*)d_in[1];
    const float* b_h0 = (const float*)d_in[2];
    const float* W_c0 = (const float*)d_in[3];
    const float* b_c0 = (const float*)d_in[4];
    const float* W_ih = (const float*)d_in[5];
    const float* W_hh = (const float*)d_in[6];
    const float* b_ih = (const float*)d_in[7];
    const float* b_hh = (const float*)d_in[8];
    float* out = (float*)d_out;

    (void)d_ws; (void)ws_size;  // no workspace used

    const int nblk = (BTOT + RPB - 1) / RPB;   // 683
    hipLaunchKernelGGL(lstm_fused, dim3(nblk), dim3(TPB), 0, stream,
                       x, W_h0, b_h0, W_c0, b_c0, W_ih, W_hh, b_ih, b_hh, out);
}